// Round 1
// baseline (1236.596 us; speedup 1.0000x reference)
//
#include <hip/hip_runtime.h>

typedef unsigned short u16;
typedef unsigned int u32;

#define PTOT 131072   // 128 images * 32*32 pixels

// ---------- helpers ----------
static __device__ __forceinline__ float quantf(float v) {
  // WAGE 8-bit: clip(round_half_even(v*128), -127, 127) / 128
  float q = rintf(v * 128.f);
  q = fmaxf(-127.f, fminf(127.f, q));
  return q * 0.0078125f;
}
static __device__ __forceinline__ u16 f2bf(float v) {
  // exact for our quantized grid values (integers*2^-7 are bf16-exact)
  return (u16)(__float_as_uint(v) >> 16);
}

// ---------- weight quantize + layout transform ----------
// in: [Co][Ci][KK] (OIHW flattened, KK = kh*3+kw or 1) -> out: [Co][KK*Ci], k = tap*Ci+ci
__global__ void wq_kernel(const float* __restrict__ w, float* __restrict__ o,
                          int Co, int Ci, int KK) {
  int idx = blockIdx.x * 256 + threadIdx.x;
  if (idx >= Co * Ci * KK) return;
  int r = idx % (Ci * KK);
  int co = idx / (Ci * KK);
  int t = r / Ci, ci = r % Ci;
  o[idx] = quantf(w[((size_t)co * Ci + ci) * KK + t]);
}

// ---------- quantize x: NCHW f32 -> NHWC bf16 (LDS transpose tile) ----------
__global__ __launch_bounds__(256) void quantx_kernel(const float* __restrict__ x,
                                                     u16* __restrict__ xq) {
  __shared__ __align__(16) u16 tile[64][72];  // 64 px x 64 ch (+pad)
  int n = blockIdx.z, hwb = blockIdx.x * 64, cb = blockIdx.y * 64;
  int lane = threadIdx.x & 63, sub = threadIdx.x >> 6;
#pragma unroll
  for (int i = 0; i < 16; ++i) {
    int c = sub + i * 4;
    float v = x[(((size_t)n * 192 + cb + c) << 10) + hwb + lane];
    tile[lane][c] = f2bf(quantf(v));
  }
  __syncthreads();
#pragma unroll
  for (int i = 0; i < 2; ++i) {
    int chunk = threadIdx.x + i * 256;
    int px = chunk >> 3, c8 = chunk & 7;
    uint4 v = *(const uint4*)&tile[px][c8 * 8];
    *(uint4*)&xq[(((size_t)n << 10) + hwb + px) * 192 + cb + c8 * 8] = v;
  }
}

// ---------- maxpool 3x3 s1 p1 on quantized NHWC bf16 ----------
// (quantize and max commute: both monotone)
__global__ __launch_bounds__(256) void pool_kernel(const u16* __restrict__ xq,
                                                   u16* __restrict__ xpq) {
  int idx = blockIdx.x * 256 + threadIdx.x;
  int c8 = idx % 24;        // 192 channels / 8
  int p = idx / 24;
  int n = p >> 10, hw = p & 1023, h = hw >> 5, w = hw & 31;
  float m[8];
#pragma unroll
  for (int j = 0; j < 8; ++j) m[j] = -1e30f;
  for (int dh = -1; dh <= 1; ++dh) {
    int hh = h + dh; if (hh < 0 || hh > 31) continue;
    for (int dw = -1; dw <= 1; ++dw) {
      int ww = w + dw; if (ww < 0 || ww > 31) continue;
      uint4 v = *(const uint4*)&xq[((((size_t)n << 5) + hh) * 32 + ww) * 192 + c8 * 8];
      u32 a[4] = {v.x, v.y, v.z, v.w};
#pragma unroll
      for (int t = 0; t < 4; ++t) {
        m[t * 2]     = fmaxf(m[t * 2],     __uint_as_float(a[t] << 16));
        m[t * 2 + 1] = fmaxf(m[t * 2 + 1], __uint_as_float(a[t] & 0xffff0000u));
      }
    }
  }
  uint4 o;
  u32* oa = &o.x;
#pragma unroll
  for (int t = 0; t < 4; ++t)
    oa[t] = (u32)f2bf(m[t * 2]) | ((u32)f2bf(m[t * 2 + 1]) << 16);
  *(uint4*)&xpq[(size_t)p * 192 + c8 * 8] = o;
}

// ---------- conv engine (fp32 FMA, weights via scalar loads) ----------
// xin: bf16; KK==1: [PTOT][CI] ; KK==9: [N][34][34][CI] zero-padded
// wv: f32 [Co][KK*CI]; y: f32 planar [Co][PTOT]; one pixel per thread.
template <int CI, int KK, int COB>
__global__ __launch_bounds__(256) void conv_kernel(const u16* __restrict__ xin,
                                                   const float* __restrict__ wv,
                                                   const float* __restrict__ bias,
                                                   float* __restrict__ y) {
  constexpr int CS = (CI < 32) ? CI : 32;   // k-chunk size (divides CI)
  constexpr int KTOT = KK * CI;
  constexpr int NCH = KTOT / CS;
  constexpr int NV = CS / 8;                // uint4 per chunk

  const int p = blockIdx.x * 256 + threadIdx.x;
  const int cob0 = blockIdx.y * COB;
  const int n = p >> 10, hw = p & 1023, h = hw >> 5, w = hw & 31;

  auto chunk_src = [&](int c) -> const u16* {
    int k0 = c * CS;
    if (KK == 1) {
      return xin + (size_t)p * CI + k0;
    } else {
      int tap = k0 / CI, ci0 = k0 % CI;
      int dh = tap / 3, dw = tap % 3;
      return xin + ((size_t)((n * 34 + h + dh) * 34) + (w + dw)) * CI + ci0;
    }
  };

  uint4 raw[NV], nxt[NV];
  {
    const u16* s = chunk_src(0);
#pragma unroll
    for (int t = 0; t < NV; ++t) raw[t] = *(const uint4*)(s + t * 8);
  }

  float acc[COB];
#pragma unroll
  for (int i = 0; i < COB; ++i) acc[i] = 0.f;

#pragma unroll 1
  for (int c = 0; c < NCH; ++c) {
    float xr[CS];
#pragma unroll
    for (int t = 0; t < NV; ++t) {
      u32 a[4] = {raw[t].x, raw[t].y, raw[t].z, raw[t].w};
#pragma unroll
      for (int e = 0; e < 4; ++e) {
        xr[t * 8 + 2 * e]     = __uint_as_float(a[e] << 16);
        xr[t * 8 + 2 * e + 1] = __uint_as_float(a[e] & 0xffff0000u);
      }
    }
    if (c + 1 < NCH) {
      const u16* s = chunk_src(c + 1);
#pragma unroll
      for (int t = 0; t < NV; ++t) nxt[t] = *(const uint4*)(s + t * 8);
    }
    const float* wb = wv + (size_t)cob0 * KTOT + c * CS;
#pragma unroll
    for (int co = 0; co < COB; ++co) {
      float a = acc[co];
      const float* wr = wb + (size_t)co * KTOT;  // wave-uniform -> s_load
#pragma unroll
      for (int j = 0; j < CS; ++j) a = fmaf(xr[j], wr[j], a);
      acc[co] = a;
    }
#pragma unroll
    for (int t = 0; t < NV; ++t) raw[t] = nxt[t];
  }

#pragma unroll
  for (int co = 0; co < COB; ++co)
    y[(size_t)(cob0 + co) * PTOT + p] = acc[co] + bias[cob0 + co];
}

// ---------- per-channel sum / sumsq over [co][PTOT] ----------
__global__ __launch_bounds__(256) void stats_kernel(const float* __restrict__ y,
                                                    double* __restrict__ st) {
  int co = blockIdx.y;
  const float* yp = y + (size_t)co * PTOT + blockIdx.x * 4096;
  double s1 = 0., s2 = 0.;
#pragma unroll
  for (int i = 0; i < 16; ++i) {
    float v = yp[threadIdx.x + i * 256];
    s1 += v;
    s2 += (double)v * v;
  }
#pragma unroll
  for (int o = 32; o > 0; o >>= 1) {
    s1 += __shfl_down(s1, o);
    s2 += __shfl_down(s2, o);
  }
  __shared__ double ls[8];
  int wid = threadIdx.x >> 6;
  if ((threadIdx.x & 63) == 0) { ls[wid * 2] = s1; ls[wid * 2 + 1] = s2; }
  __syncthreads();
  if (threadIdx.x == 0) {
    atomicAdd(&st[co * 2],     ls[0] + ls[2] + ls[4] + ls[6]);
    atomicAdd(&st[co * 2 + 1], ls[1] + ls[3] + ls[5] + ls[7]);
  }
}

// ---------- BN coefficients: z = y*C0 + C1 ----------
__global__ void coef_kernel(const double* __restrict__ st, const float* __restrict__ g,
                            const float* __restrict__ be, float2* __restrict__ cf, int Co) {
  int co = threadIdx.x;
  if (co >= Co) return;
  double m = st[co * 2] * (1.0 / PTOT);
  double v = st[co * 2 + 1] * (1.0 / PTOT) - m * m;
  double inv = 1.0 / sqrt(v + 1e-5);
  double c0 = (double)g[co] * inv;
  double c1 = (double)be[co] - m * c0;
  cf[co] = make_float2((float)c0, (float)c1);
}

// ---------- BN+ReLU -> final output (NCHW f32 at concat offset) ----------
__global__ __launch_bounds__(256) void bnq_out_kernel(const float* __restrict__ y,
                                                      const float2* __restrict__ cf,
                                                      float* __restrict__ out, int cog0) {
  int n = blockIdx.x, co = blockIdx.y;
  float2 cc = cf[co];
  const float* yp = y + (size_t)co * PTOT + ((size_t)n << 10);
  float* op = out + (((size_t)n * 256) + cog0 + co) * 1024;
#pragma unroll
  for (int i = 0; i < 4; ++i) {
    int t = threadIdx.x + i * 256;
    op[t] = fmaxf(fmaf(yp[t], cc.x, cc.y), 0.f);
  }
}

// ---------- BN+ReLU+quantize -> padded NHWC bf16 (for next conv) ----------
template <int CO>
__global__ __launch_bounds__(256) void bnq_pad_kernel(const float* __restrict__ y,
                                                      const float2* __restrict__ cf,
                                                      u16* __restrict__ q) {
  __shared__ __align__(16) u16 tile[64][CO + 8];
  int p0 = blockIdx.x * 64;
  int lane = threadIdx.x & 63, sub = threadIdx.x >> 6;
#pragma unroll
  for (int i = 0; i < CO / 4; ++i) {
    int co = sub + i * 4;
    float2 cc = cf[co];
    float z = fmaxf(fmaf(y[(size_t)co * PTOT + p0 + lane], cc.x, cc.y), 0.f);
    float qv = fminf(rintf(z * 128.f), 127.f) * 0.0078125f;  // z>=0 after relu
    tile[lane][co] = f2bf(qv);
  }
  __syncthreads();
  for (int chunk = threadIdx.x; chunk < 64 * (CO / 8); chunk += 256) {
    int px = chunk / (CO / 8), c8 = chunk % (CO / 8);
    int p = p0 + px;
    int n = p >> 10, hw = p & 1023, h = hw >> 5, w = hw & 31;
    size_t dst = (((size_t)n * 34 + h + 1) * 34 + (w + 1)) * CO + c8 * 8;
    *(uint4*)&q[dst] = *(const uint4*)&tile[px][c8 * 8];
  }
}

extern "C" void kernel_launch(void* const* d_in, const int* in_sizes, int n_in,
                              void* d_out, int out_size, void* d_ws, size_t ws_size,
                              hipStream_t stream) {
  const float* x = (const float*)d_in[0];
  float* out = (float*)d_out;
  char* ws = (char*)d_ws;

  // ---- workspace layout (total 168,451,072 B ~= 160.6 MiB) ----
  if (ws_size < 168451072ull) return;  // capacity failure -> visible as poison
  u16* xq   = (u16*)ws;                        // 50,331,648 B  [PTOT][192] bf16
  u16* xpq  = (u16*)(ws + 50331648ull);        // 50,331,648 B  (pooled; later aliased)
  u16* q2a  = xpq;                             // 28,409,856 B  [128][34][34][96]
  u16* q3a  = (u16*)(ws + 78741504ull);        //  4,734,976 B  [128][34][34][16]
  u16* q3b  = (u16*)(ws + 83476480ull);        //  9,469,952 B  [128][34][34][32]
  float* yt = (float*)(ws + 100663296ull);     // 67,108,864 B  [<=128][PTOT] f32
  float* wqb = (float*)(ws + 167772160ull);    //    657,408 B  quantized weights
  double* st = (double*)(ws + 168429568ull);   //     14,336 B  7 x 128 x {sum,sumsq}
  float2* cf = (float2*)(ws + 168443904ull);   //      7,168 B  7 x 128 x {C0,C1}

  hipMemsetAsync(st, 0, 14336, stream);

  // ---- quantize weights: {in_idx, Co, Ci, KK, f32_offset} ----
  const int wspec[7][5] = {
      {1, 64, 192, 1, 0},       {5, 96, 192, 1, 12288},  {9, 128, 96, 9, 30720},
      {13, 16, 192, 1, 141312}, {17, 32, 16, 9, 144384}, {21, 32, 32, 9, 148992},
      {25, 32, 192, 1, 158208},
  };
  for (int i = 0; i < 7; ++i) {
    int tot = wspec[i][1] * wspec[i][2] * wspec[i][3];
    wq_kernel<<<(tot + 255) / 256, 256, 0, stream>>>(
        (const float*)d_in[wspec[i][0]], wqb + wspec[i][4], wspec[i][1], wspec[i][2],
        wspec[i][3]);
  }

  quantx_kernel<<<dim3(16, 3, 128), 256, 0, stream>>>(x, xq);
  pool_kernel<<<12288, 256, 0, stream>>>(xq, xpq);

  // ---- b4 (slot 6): pooled 1x1 192->32, out channels 224..255 (runs first: xpq dies after)
  conv_kernel<192, 1, 16><<<dim3(512, 2), 256, 0, stream>>>(xpq, wqb + 158208,
                                                            (const float*)d_in[26], yt);
  stats_kernel<<<dim3(32, 32), 256, 0, stream>>>(yt, st + 6 * 256);
  coef_kernel<<<1, 128, 0, stream>>>(st + 6 * 256, (const float*)d_in[27],
                                     (const float*)d_in[28], cf + 6 * 128, 32);
  bnq_out_kernel<<<dim3(128, 32), 256, 0, stream>>>(yt, cf + 6 * 128, out, 224);

  // zero padded q buffers (borders must be 0); aliases xpq which is now dead
  hipMemsetAsync(ws + 50331648ull, 0, 42614784ull, stream);

  // ---- b1 (slot 0): 1x1 192->64, out 0..63
  conv_kernel<192, 1, 32><<<dim3(512, 2), 256, 0, stream>>>(xq, wqb + 0,
                                                            (const float*)d_in[2], yt);
  stats_kernel<<<dim3(32, 64), 256, 0, stream>>>(yt, st);
  coef_kernel<<<1, 128, 0, stream>>>(st, (const float*)d_in[3], (const float*)d_in[4], cf, 64);
  bnq_out_kernel<<<dim3(128, 64), 256, 0, stream>>>(yt, cf, out, 0);

  // ---- b2a (slot 1): 1x1 192->96 -> q2a
  conv_kernel<192, 1, 48><<<dim3(512, 2), 256, 0, stream>>>(xq, wqb + 12288,
                                                            (const float*)d_in[6], yt);
  stats_kernel<<<dim3(32, 96), 256, 0, stream>>>(yt, st + 1 * 256);
  coef_kernel<<<1, 128, 0, stream>>>(st + 1 * 256, (const float*)d_in[7],
                                     (const float*)d_in[8], cf + 1 * 128, 96);
  bnq_pad_kernel<96><<<2048, 256, 0, stream>>>(yt, cf + 1 * 128, q2a);

  // ---- b2b (slot 2): 3x3 96->128, out 64..191
  conv_kernel<96, 9, 32><<<dim3(512, 4), 256, 0, stream>>>(q2a, wqb + 30720,
                                                           (const float*)d_in[10], yt);
  stats_kernel<<<dim3(32, 128), 256, 0, stream>>>(yt, st + 2 * 256);
  coef_kernel<<<1, 128, 0, stream>>>(st + 2 * 256, (const float*)d_in[11],
                                     (const float*)d_in[12], cf + 2 * 128, 128);
  bnq_out_kernel<<<dim3(128, 128), 256, 0, stream>>>(yt, cf + 2 * 128, out, 64);

  // ---- b3a (slot 3): 1x1 192->16 -> q3a
  conv_kernel<192, 1, 8><<<dim3(512, 2), 256, 0, stream>>>(xq, wqb + 141312,
                                                           (const float*)d_in[14], yt);
  stats_kernel<<<dim3(32, 16), 256, 0, stream>>>(yt, st + 3 * 256);
  coef_kernel<<<1, 128, 0, stream>>>(st + 3 * 256, (const float*)d_in[15],
                                     (const float*)d_in[16], cf + 3 * 128, 16);
  bnq_pad_kernel<16><<<2048, 256, 0, stream>>>(yt, cf + 3 * 128, q3a);

  // ---- b3b (slot 4): 3x3 16->32 -> q3b
  conv_kernel<16, 9, 16><<<dim3(512, 2), 256, 0, stream>>>(q3a, wqb + 144384,
                                                           (const float*)d_in[18], yt);
  stats_kernel<<<dim3(32, 32), 256, 0, stream>>>(yt, st + 4 * 256);
  coef_kernel<<<1, 128, 0, stream>>>(st + 4 * 256, (const float*)d_in[19],
                                     (const float*)d_in[20], cf + 4 * 128, 32);
  bnq_pad_kernel<32><<<2048, 256, 0, stream>>>(yt, cf + 4 * 128, q3b);

  // ---- b3c (slot 5): 3x3 32->32, out 192..223
  conv_kernel<32, 9, 16><<<dim3(512, 2), 256, 0, stream>>>(q3b, wqb + 148992,
                                                           (const float*)d_in[22], yt);
  stats_kernel<<<dim3(32, 32), 256, 0, stream>>>(yt, st + 5 * 256);
  coef_kernel<<<1, 128, 0, stream>>>(st + 5 * 256, (const float*)d_in[23],
                                     (const float*)d_in[24], cf + 5 * 128, 32);
  bnq_out_kernel<<<dim3(128, 32), 256, 0, stream>>>(yt, cf + 5 * 128, out, 192);
}

// Round 2
// 425.603 us; speedup vs baseline: 2.9055x; 2.9055x over previous
//
#include <hip/hip_runtime.h>

typedef unsigned short u16;
typedef unsigned int u32;
typedef __attribute__((ext_vector_type(8))) short bf16x8;
typedef __attribute__((ext_vector_type(4))) float f32x4;

#define PTOT 131072   // 128 images * 32*32 pixels

// ---------- helpers ----------
static __device__ __forceinline__ float quantf(float v) {
  // WAGE 8-bit: clip(round_half_even(v*128), -127, 127) / 128
  float q = rintf(v * 128.f);
  q = fmaxf(-127.f, fminf(127.f, q));
  return q * 0.0078125f;
}
static __device__ __forceinline__ u16 f2bf(float v) {
  // exact for our quantized grid values (integers*2^-7 are bf16-exact)
  return (u16)(__float_as_uint(v) >> 16);
}

// ---------- weight quantize + MFMA fragment packing ----------
// output element idx over [NCH][NF][64 lanes][8]; value = W[co][k] quantized,
// co = nf*16 + (lane&15), k = c*32 + (lane>>4)*8 + j; k -> (tap, ci) over padded CI.
__global__ void wpack_kernel(const float* __restrict__ w, u16* __restrict__ o,
                             int CIr, int CIp, int KH, int Co, int tot) {
  int idx = blockIdx.x * 256 + threadIdx.x;
  if (idx >= tot) return;
  int j = idx & 7, lane = (idx >> 3) & 63, f = idx >> 9;
  int NF = Co >> 4;
  int c = f / NF, nf = f - c * NF;
  int co = nf * 16 + (lane & 15);
  int k = c * 32 + ((lane >> 4) << 3) + j;
  int tap = k / CIp, ci = k - tap * CIp;
  u16 val = 0;
  if (ci < CIr) {
    int kh = tap / 3, kw = tap - kh * 3;  // KH==1 -> tap==0 -> kh=kw=0
    val = f2bf(quantf(w[(((size_t)co * CIr + ci) * KH + kh) * KH + kw]));
  }
  o[idx] = val;
}

// ---------- quantize x: NCHW f32 -> NHWC bf16 (LDS transpose tile) ----------
__global__ __launch_bounds__(256) void quantx_kernel(const float* __restrict__ x,
                                                     u16* __restrict__ xq) {
  __shared__ __align__(16) u16 tile[64][72];  // 64 px x 64 ch (+pad)
  int n = blockIdx.z, hwb = blockIdx.x * 64, cb = blockIdx.y * 64;
  int lane = threadIdx.x & 63, sub = threadIdx.x >> 6;
#pragma unroll
  for (int i = 0; i < 16; ++i) {
    int c = sub + i * 4;
    float v = x[(((size_t)n * 192 + cb + c) << 10) + hwb + lane];
    tile[lane][c] = f2bf(quantf(v));
  }
  __syncthreads();
#pragma unroll
  for (int i = 0; i < 2; ++i) {
    int chunk = threadIdx.x + i * 256;
    int px = chunk >> 3, c8 = chunk & 7;
    uint4 v = *(const uint4*)&tile[px][c8 * 8];
    *(uint4*)&xq[(((size_t)n << 10) + hwb + px) * 192 + cb + c8 * 8] = v;
  }
}

// ---------- maxpool 3x3 s1 p1 on quantized NHWC bf16 ----------
__global__ __launch_bounds__(256) void pool_kernel(const u16* __restrict__ xq,
                                                   u16* __restrict__ xpq) {
  int idx = blockIdx.x * 256 + threadIdx.x;
  int c8 = idx % 24;
  int p = idx / 24;
  int n = p >> 10, hw = p & 1023, h = hw >> 5, w = hw & 31;
  float m[8];
#pragma unroll
  for (int j = 0; j < 8; ++j) m[j] = -1e30f;
  for (int dh = -1; dh <= 1; ++dh) {
    int hh = h + dh; if (hh < 0 || hh > 31) continue;
    for (int dw = -1; dw <= 1; ++dw) {
      int ww = w + dw; if (ww < 0 || ww > 31) continue;
      uint4 v = *(const uint4*)&xq[((((size_t)n << 5) + hh) * 32 + ww) * 192 + c8 * 8];
      u32 a[4] = {v.x, v.y, v.z, v.w};
#pragma unroll
      for (int t = 0; t < 4; ++t) {
        m[t * 2]     = fmaxf(m[t * 2],     __uint_as_float(a[t] << 16));
        m[t * 2 + 1] = fmaxf(m[t * 2 + 1], __uint_as_float(a[t] & 0xffff0000u));
      }
    }
  }
  uint4 o;
  u32* oa = &o.x;
#pragma unroll
  for (int t = 0; t < 4; ++t)
    oa[t] = (u32)f2bf(m[t * 2]) | ((u32)f2bf(m[t * 2 + 1]) << 16);
  *(uint4*)&xpq[(size_t)p * 192 + c8 * 8] = o;
}

// ---------- MFMA implicit-GEMM conv ----------
// xin bf16: KK==1: [PTOT][CI]; KK==9: [128][34][34][CI] zero-padded.
// bp: packed B fragments [K/32][CO/16][64][8] bf16. y: f32 planar [CO][PTOT].
// 4 waves/block: WM=4/NS m-groups x NS n-groups; wave = MF*16 px x CO/NS cols.
template <int CI, int KK, int CO, int MF, int NS>
__global__ __launch_bounds__(256) void mconv_kernel(const u16* __restrict__ xin,
                                                    const u16* __restrict__ bp,
                                                    float* __restrict__ y) {
  constexpr int NCH = KK * CI / 32;
  constexpr int NFT = CO / 16;
  constexpr int NFW = NFT / NS;
  constexpr int WM = 4 / NS;

  const int lane = threadIdx.x & 63;
  const int wave = threadIdx.x >> 6;
  const int wm = wave / NS, wn = wave % NS;
  const int mbase = blockIdx.x * (WM * MF * 16) + wm * (MF * 16);
  const int cob = wn * (16 * NFW);

  uint abase[MF];
#pragma unroll
  for (int mf = 0; mf < MF; ++mf) {
    int p = mbase + mf * 16 + (lane & 15);
    if (KK == 1) {
      abase[mf] = (uint)p * (CI * 2);
    } else {
      int n = p >> 10, hw = p & 1023, h = hw >> 5, w = hw & 31;
      // tap (0,0) reads padded row h (= input row h-1), col w
      abase[mf] = (uint)((n * 34 + h) * 34 + w) * (CI * 2);
    }
  }
  const uint klane = (uint)(lane >> 4) * 16u;  // k-subgroup byte offset
  const uint blane = (uint)lane * 16u;

  f32x4 acc[MF][NFW];
#pragma unroll
  for (int i = 0; i < MF; ++i)
#pragma unroll
    for (int j = 0; j < NFW; ++j) acc[i][j] = {0.f, 0.f, 0.f, 0.f};

  auto chunk = [&](int c) {
    uint koff;
    if (KK == 1) {
      koff = (uint)c * 64u;
    } else {
      int tap = (c * 32) / CI, ci0 = (c * 32) % CI;  // CI>=32: no straddle
      koff = (uint)(((tap / 3) * 34 + (tap % 3)) * CI + ci0) * 2u;
    }
    bf16x8 af[MF];
#pragma unroll
    for (int mf = 0; mf < MF; ++mf)
      af[mf] = *(const bf16x8*)((const char*)xin + (abase[mf] + koff + klane));
    bf16x8 bfr[NFW];
#pragma unroll
    for (int nf = 0; nf < NFW; ++nf)
      bfr[nf] = *(const bf16x8*)((const char*)bp +
                                 ((uint)(c * NFT + wn * NFW + nf) * 1024u + blane));
#pragma unroll
    for (int mf = 0; mf < MF; ++mf)
#pragma unroll
      for (int nf = 0; nf < NFW; ++nf)
        acc[mf][nf] = __builtin_amdgcn_mfma_f32_16x16x32_bf16(af[mf], bfr[nf],
                                                              acc[mf][nf], 0, 0, 0);
  };

  if (KK == 1) {
#pragma unroll
    for (int c = 0; c < NCH; ++c) chunk(c);
  } else {
#pragma unroll 3
    for (int c = 0; c < NCH; ++c) chunk(c);
  }

#pragma unroll
  for (int mf = 0; mf < MF; ++mf)
#pragma unroll
    for (int nf = 0; nf < NFW; ++nf) {
      int co = cob + nf * 16 + (lane & 15);
      int pix = mbase + mf * 16 + (lane >> 4) * 4;
      *(f32x4*)&y[(size_t)co * PTOT + pix] = acc[mf][nf];
    }
}

// ---------- per-channel sum / sumsq over [co][PTOT] ----------
__global__ __launch_bounds__(256) void stats_kernel(const float* __restrict__ y,
                                                    double* __restrict__ st) {
  int co = blockIdx.y;
  const float* yp = y + (size_t)co * PTOT + blockIdx.x * 4096;
  double s1 = 0., s2 = 0.;
#pragma unroll
  for (int i = 0; i < 16; ++i) {
    float v = yp[threadIdx.x + i * 256];
    s1 += v;
    s2 += (double)v * v;
  }
#pragma unroll
  for (int o = 32; o > 0; o >>= 1) {
    s1 += __shfl_down(s1, o);
    s2 += __shfl_down(s2, o);
  }
  __shared__ double ls[8];
  int wid = threadIdx.x >> 6;
  if ((threadIdx.x & 63) == 0) { ls[wid * 2] = s1; ls[wid * 2 + 1] = s2; }
  __syncthreads();
  if (threadIdx.x == 0) {
    atomicAdd(&st[co * 2],     ls[0] + ls[2] + ls[4] + ls[6]);
    atomicAdd(&st[co * 2 + 1], ls[1] + ls[3] + ls[5] + ls[7]);
  }
}

// ---------- BN coefficients: z = y*C0 + C1 (bias dropped: BN absorbs it) ----------
__global__ void coef_kernel(const double* __restrict__ st, const float* __restrict__ g,
                            const float* __restrict__ be, float2* __restrict__ cf, int Co) {
  int co = threadIdx.x;
  if (co >= Co) return;
  double m = st[co * 2] * (1.0 / PTOT);
  double v = st[co * 2 + 1] * (1.0 / PTOT) - m * m;
  double inv = 1.0 / sqrt(v + 1e-5);
  double c0 = (double)g[co] * inv;
  double c1 = (double)be[co] - m * c0;
  cf[co] = make_float2((float)c0, (float)c1);
}

// ---------- BN+ReLU -> final output (NCHW f32 at concat offset) ----------
__global__ __launch_bounds__(256) void bnq_out_kernel(const float* __restrict__ y,
                                                      const float2* __restrict__ cf,
                                                      float* __restrict__ out, int cog0) {
  int n = blockIdx.x, co = blockIdx.y;
  float2 cc = cf[co];
  const float* yp = y + (size_t)co * PTOT + ((size_t)n << 10);
  float* op = out + (((size_t)n * 256) + cog0 + co) * 1024;
#pragma unroll
  for (int i = 0; i < 4; ++i) {
    int t = threadIdx.x + i * 256;
    op[t] = fmaxf(fmaf(yp[t], cc.x, cc.y), 0.f);
  }
}

// ---------- BN+ReLU+quantize -> padded NHWC bf16 (CO real ch, COP stored) ----------
template <int CO, int COP>
__global__ __launch_bounds__(256) void bnq_pad_kernel(const float* __restrict__ y,
                                                      const float2* __restrict__ cf,
                                                      u16* __restrict__ q) {
  __shared__ __align__(16) u16 tile[64][COP + 8];
  int p0 = blockIdx.x * 64;
  int lane = threadIdx.x & 63, sub = threadIdx.x >> 6;
#pragma unroll
  for (int i = 0; i < COP / 4; ++i) {
    int co = sub + i * 4;
    u16 outv = 0;
    if (CO == COP || co < CO) {
      float2 cc = cf[co];
      float z = fmaxf(fmaf(y[(size_t)co * PTOT + p0 + lane], cc.x, cc.y), 0.f);
      float qv = fminf(rintf(z * 128.f), 127.f) * 0.0078125f;  // z>=0 after relu
      outv = f2bf(qv);
    }
    tile[lane][co] = outv;
  }
  __syncthreads();
  for (int chunk = threadIdx.x; chunk < 64 * (COP / 8); chunk += 256) {
    int px = chunk / (COP / 8), c8 = chunk % (COP / 8);
    int p = p0 + px;
    int n = p >> 10, hw = p & 1023, h = hw >> 5, w = hw & 31;
    size_t dst = (((size_t)n * 34 + h + 1) * 34 + (w + 1)) * COP + c8 * 8;
    *(uint4*)&q[dst] = *(const uint4*)&tile[px][c8 * 8];
  }
}

extern "C" void kernel_launch(void* const* d_in, const int* in_sizes, int n_in,
                              void* d_out, int out_size, void* d_ws, size_t ws_size,
                              hipStream_t stream) {
  const float* x = (const float*)d_in[0];
  float* out = (float*)d_out;
  char* ws = (char*)d_ws;

  // ---- workspace layout (total 168,131,584 B) ----
  if (ws_size < 168131584ull) return;
  u16* xq  = (u16*)ws;                       // [PTOT][192] bf16
  u16* xpq = (u16*)(ws + 50331648ull);       // pooled [PTOT][192]; window reused:
  u16* q2a = xpq;                            //   [128][34][34][96]  = 28,409,856 B
  u16* q3a = (u16*)(ws + 78741504ull);       //   [128][34][34][32]  =  9,469,952 B
  u16* q3b = (u16*)(ws + 88211456ull);       //   [128][34][34][32]  =  9,469,952 B
  float* yt = (float*)(ws + 100663296ull);   // [<=128][PTOT] f32    = 67,108,864 B
  u16* bpk = (u16*)(ws + 167772160ull);      // packed weights 337,920 B
  double* st = (double*)(ws + 168110080ull); // 7 x 128 x {sum,sumsq}
  float2* cf = (float2*)(ws + 168124416ull); // 7 x 128 x {C0,C1}

  hipMemsetAsync(st, 0, 14336, stream);

  // ---- pack weights: {in_idx, Co, CIr, CIp, KH, elem_offset} ----
  const int wspec[7][6] = {
      {1, 64, 192, 192, 1, 0},       {5, 96, 192, 192, 1, 12288},
      {9, 128, 96, 96, 3, 30720},    {13, 16, 192, 192, 1, 141312},
      {17, 32, 16, 32, 3, 144384},   {21, 32, 32, 32, 3, 153600},
      {25, 32, 192, 192, 1, 162816},
  };
  for (int i = 0; i < 7; ++i) {
    int tot = wspec[i][1] * wspec[i][3] * (wspec[i][4] == 3 ? 9 : 1);
    wpack_kernel<<<(tot + 255) / 256, 256, 0, stream>>>(
        (const float*)d_in[wspec[i][0]], bpk + wspec[i][5], wspec[i][2], wspec[i][3],
        wspec[i][4], wspec[i][1], tot);
  }

  quantx_kernel<<<dim3(16, 3, 128), 256, 0, stream>>>(x, xq);
  pool_kernel<<<12288, 256, 0, stream>>>(xq, xpq);

  // ---- b4 (slot 6): pooled 1x1 192->32, out 224..255 (xpq dies after)
  mconv_kernel<192, 1, 32, 4, 1><<<512, 256, 0, stream>>>(xpq, bpk + 162816, yt);
  stats_kernel<<<dim3(32, 32), 256, 0, stream>>>(yt, st + 6 * 256);
  coef_kernel<<<1, 128, 0, stream>>>(st + 6 * 256, (const float*)d_in[27],
                                     (const float*)d_in[28], cf + 6 * 128, 32);
  bnq_out_kernel<<<dim3(128, 32), 256, 0, stream>>>(yt, cf + 6 * 128, out, 224);

  // zero padded q buffers (borders + b3a channel pad); aliases dead xpq
  hipMemsetAsync(ws + 50331648ull, 0, 47349760ull, stream);

  // ---- b1 (slot 0): 1x1 192->64, out 0..63
  mconv_kernel<192, 1, 64, 4, 1><<<512, 256, 0, stream>>>(xq, bpk + 0, yt);
  stats_kernel<<<dim3(32, 64), 256, 0, stream>>>(yt, st);
  coef_kernel<<<1, 128, 0, stream>>>(st, (const float*)d_in[3], (const float*)d_in[4], cf, 64);
  bnq_out_kernel<<<dim3(128, 64), 256, 0, stream>>>(yt, cf, out, 0);

  // ---- b2a (slot 1): 1x1 192->96 -> q2a
  mconv_kernel<192, 1, 96, 4, 2><<<1024, 256, 0, stream>>>(xq, bpk + 12288, yt);
  stats_kernel<<<dim3(32, 96), 256, 0, stream>>>(yt, st + 1 * 256);
  coef_kernel<<<1, 128, 0, stream>>>(st + 1 * 256, (const float*)d_in[7],
                                     (const float*)d_in[8], cf + 1 * 128, 96);
  bnq_pad_kernel<96, 96><<<2048, 256, 0, stream>>>(yt, cf + 1 * 128, q2a);

  // ---- b2b (slot 2): 3x3 96->128, out 64..191
  mconv_kernel<96, 9, 128, 4, 2><<<1024, 256, 0, stream>>>(q2a, bpk + 30720, yt);
  stats_kernel<<<dim3(32, 128), 256, 0, stream>>>(yt, st + 2 * 256);
  coef_kernel<<<1, 128, 0, stream>>>(st + 2 * 256, (const float*)d_in[11],
                                     (const float*)d_in[12], cf + 2 * 128, 128);
  bnq_out_kernel<<<dim3(128, 128), 256, 0, stream>>>(yt, cf + 2 * 128, out, 64);

  // ---- b3a (slot 3): 1x1 192->16 -> q3a (stored as 32ch, upper 16 zero)
  mconv_kernel<192, 1, 16, 4, 1><<<512, 256, 0, stream>>>(xq, bpk + 141312, yt);
  stats_kernel<<<dim3(32, 16), 256, 0, stream>>>(yt, st + 3 * 256);
  coef_kernel<<<1, 128, 0, stream>>>(st + 3 * 256, (const float*)d_in[15],
                                     (const float*)d_in[16], cf + 3 * 128, 16);
  bnq_pad_kernel<16, 32><<<2048, 256, 0, stream>>>(yt, cf + 3 * 128, q3a);

  // ---- b3b (slot 4): 3x3 16->32 (CI padded to 32) -> q3b
  mconv_kernel<32, 9, 32, 4, 1><<<512, 256, 0, stream>>>(q3a, bpk + 144384, yt);
  stats_kernel<<<dim3(32, 32), 256, 0, stream>>>(yt, st + 4 * 256);
  coef_kernel<<<1, 128, 0, stream>>>(st + 4 * 256, (const float*)d_in[19],
                                     (const float*)d_in[20], cf + 4 * 128, 32);
  bnq_pad_kernel<32, 32><<<2048, 256, 0, stream>>>(yt, cf + 4 * 128, q3b);

  // ---- b3c (slot 5): 3x3 32->32, out 192..223
  mconv_kernel<32, 9, 32, 4, 1><<<512, 256, 0, stream>>>(q3b, bpk + 153600, yt);
  stats_kernel<<<dim3(32, 32), 256, 0, stream>>>(yt, st + 5 * 256);
  coef_kernel<<<1, 128, 0, stream>>>(st + 5 * 256, (const float*)d_in[23],
                                     (const float*)d_in[24], cf + 5 * 128, 32);
  bnq_out_kernel<<<dim3(128, 32), 256, 0, stream>>>(yt, cf + 5 * 128, out, 192);
}